// Round 8
// baseline (57.548 us; speedup 1.0000x reference)
//
#include <hip/hip_runtime.h>

#define D 128
#define CHUNK 64
#define NW 4                 // waves per block
#define MAX_TYPES 1024
#define MAX_B 8192
#define MARGIN 1.0f

// ws layout (int units)
#define WS_NITEMS 0
#define WS_ORDER  64                     // B ints (slot -> sample idx)
#define WS_ITEMS  8448                   // int4 x <=2048
#define WS_NEEDED ((size_t)(WS_ITEMS + 4 * 2048) * 4)

// ---------------- fused grouping kernel (1 block, 1024 thr) ----------------

__global__ __launch_bounds__(1024) void group_kernel(
    const int* __restrict__ type_r, int* __restrict__ ws,
    float* __restrict__ out, int B, int ntype)
{
    __shared__ int hist[MAX_TYPES];
    __shared__ int typec[MAX_B];
    __shared__ int wsum[16], wsum2[16];
    const int tid = threadIdx.x;
    const int lane = tid & 63;
    const int wv = tid >> 6;

    if (tid == 0) out[0] = 0.0f;
    hist[tid] = 0;
    __syncthreads();

    const int B4 = B >> 2;
    const int4* t4p = (const int4*)type_r;
    for (int i = tid; i < B4; i += 1024) {
        const int4 t = t4p[i];
        typec[i * 4 + 0] = t.x; atomicAdd(&hist[t.x], 1);
        typec[i * 4 + 1] = t.y; atomicAdd(&hist[t.y], 1);
        typec[i * 4 + 2] = t.z; atomicAdd(&hist[t.z], 1);
        typec[i * 4 + 3] = t.w; atomicAdd(&hist[t.w], 1);
    }
    for (int i = (B4 << 2) + tid; i < B; i += 1024) {
        const int t = type_r[i];
        typec[i] = t;
        atomicAdd(&hist[t], 1);
    }
    __syncthreads();

    const int c  = (tid < ntype) ? hist[tid] : 0;
    const int ic = (c + CHUNK - 1) / CHUNK;
    int vc = c, vic = ic;
    #pragma unroll
    for (int off = 1; off < 64; off <<= 1) {
        const int tc  = __shfl_up(vc,  off);
        const int tic = __shfl_up(vic, off);
        if (lane >= off) { vc += tc; vic += tic; }
    }
    if (lane == 63) { wsum[wv] = vc; wsum2[wv] = vic; }
    __syncthreads();
    if (wv == 0 && lane < 16) {
        int a = wsum[lane], b = wsum2[lane];
        #pragma unroll
        for (int off = 1; off < 16; off <<= 1) {
            const int ta = __shfl_up(a, off);
            const int tb = __shfl_up(b, off);
            if (lane >= off) { a += ta; b += tb; }
        }
        wsum[lane] = a; wsum2[lane] = b;
    }
    __syncthreads();
    const int base_c  = (wv ? wsum[wv - 1]  : 0) + vc - c;
    const int base_ic = (wv ? wsum2[wv - 1] : 0) + vic - ic;
    hist[tid] = base_c;                   // scatter cursor
    if (tid < ntype && ic > 0) {
        int4* items = (int4*)(ws + WS_ITEMS);
        for (int k = 0; k < ic; ++k)
            items[base_ic + k] = make_int4(tid, base_c + k * CHUNK,
                                           min(CHUNK, c - k * CHUNK), 0);
    }
    if (tid == 0) ws[WS_NITEMS] = wsum2[15];
    __syncthreads();
    for (int i = tid; i < B; i += 1024) {
        const int p = atomicAdd(&hist[typec[i]], 1);
        ws[WS_ORDER + p] = i;
    }
}

// ---------------- fused main kernel: wave-autonomous sample pairs ----------

#define BFLY5(x) { x += __shfl_xor(x, 1); x += __shfl_xor(x, 2); x += __shfl_xor(x, 4); \
                   x += __shfl_xor(x, 8); x += __shfl_xor(x, 16); }

#define FMA4(A, T, S) { (A).x = fmaf((T).x, (S), (A).x); (A).y = fmaf((T).y, (S), (A).y); \
                        (A).z = fmaf((T).z, (S), (A).z); (A).w = fmaf((T).w, (S), (A).w); }

struct SampleRegs {
    float2 e0, e1, e2, e3;   // ent rows {ph,pt,nh,nt}, elems {2l, 2l+1}
    float4 rp, rn;           // rel rows (pos, neg), cols 4cg..+3
};

__device__ __forceinline__ void fetch_sample(
    SampleRegs& S, int o,
    const float* __restrict__ ent, const float* __restrict__ rel,
    const int* __restrict__ pos_h, const int* __restrict__ pos_t,
    const int* __restrict__ pos_r, const int* __restrict__ neg_h,
    const int* __restrict__ neg_t, const int* __restrict__ neg_r,
    int l, int cg)
{
    const size_t b0 = (size_t)pos_h[o] * D;
    const size_t b1 = (size_t)pos_t[o] * D;
    const size_t b2 = (size_t)neg_h[o] * D;
    const size_t b3 = (size_t)neg_t[o] * D;
    const size_t r0 = (size_t)pos_r[o] * D;
    const size_t r1 = (size_t)neg_r[o] * D;
    S.e0 = *(const float2*)&ent[b0 + 2 * l];
    S.e1 = *(const float2*)&ent[b1 + 2 * l];
    S.e2 = *(const float2*)&ent[b2 + 2 * l];
    S.e3 = *(const float2*)&ent[b3 + 2 * l];
    S.rp = *(const float4*)&rel[r0 + 4 * cg];
    S.rn = *(const float4*)&rel[r1 + 4 * cg];
}

__device__ __forceinline__ void commit_sample(float* vbs, const SampleRegs& S, int l) {
    *(float2*)&vbs[0 * D + 2 * l] = S.e0;
    *(float2*)&vbs[1 * D + 2 * l] = S.e1;
    *(float2*)&vbs[2 * D + 2 * l] = S.e2;
    *(float2*)&vbs[3 * D + 2 * l] = S.e3;
}

// per-sample epilogue: full column sums in a[4] (roles ph,pt,nh,nt), rel in rp/rn.
// Values duplicated across 32-lane halves; BFLY5 sums each half independently.
__device__ __forceinline__ float sscore(const float4 a[4], float4 rp, float4 rn) {
    float sph = a[0].x*a[0].x + a[0].y*a[0].y + a[0].z*a[0].z + a[0].w*a[0].w;
    float spt = a[1].x*a[1].x + a[1].y*a[1].y + a[1].z*a[1].z + a[1].w*a[1].w;
    float snh = a[2].x*a[2].x + a[2].y*a[2].y + a[2].z*a[2].z + a[2].w*a[2].w;
    float snt = a[3].x*a[3].x + a[3].y*a[3].y + a[3].z*a[3].z + a[3].w*a[3].w;
    float spr = rp.x*rp.x + rp.y*rp.y + rp.z*rp.z + rp.w*rp.w;
    float snr = rn.x*rn.x + rn.y*rn.y + rn.z*rn.z + rn.w*rn.w;
    BFLY5(sph); BFLY5(spt); BFLY5(snh); BFLY5(snt); BFLY5(spr); BFLY5(snr);
    const float iph = rsqrtf(sph + 1e-12f);
    const float ipt = rsqrtf(spt + 1e-12f);
    const float inh = rsqrtf(snh + 1e-12f);
    const float itn = rsqrtf(snt + 1e-12f);
    const float ipr = rsqrtf(spr + 1e-12f);
    const float inr = rsqrtf(snr + 1e-12f);
    float z = fabsf(a[0].x*iph + rp.x*ipr - a[1].x*ipt)
            + fabsf(a[0].y*iph + rp.y*ipr - a[1].y*ipt)
            + fabsf(a[0].z*iph + rp.z*ipr - a[1].z*ipt)
            + fabsf(a[0].w*iph + rp.w*ipr - a[1].w*ipt)
            - fabsf(a[2].x*inh + rn.x*inr - a[3].x*itn)
            - fabsf(a[2].y*inh + rn.y*inr - a[3].y*itn)
            - fabsf(a[2].z*inh + rn.z*inr - a[3].z*itn)
            - fabsf(a[2].w*inh + rn.w*inr - a[3].w*itn);
    BFLY5(z);
    return fmaxf(z + MARGIN, 0.f);
}

// pair matvec: lane owns cols 4cg..+3, half h of d-range. T b128 conflict-free.
__device__ __forceinline__ void pair_score(
    const float* __restrict__ T_lds, const float* __restrict__ vbw,
    const SampleRegs& A, const SampleRegs& Bq,
    int h, int cg, bool hasB, float& wl)
{
    const float4* __restrict__ T4 = (const float4*)T_lds;        // [row][32]
    const float4* __restrict__ vA = (const float4*)vbw;          // [4][32]
    const float4* __restrict__ vB = vA + 128;                    // sample B
    float4 aA[4], aB[4];
    #pragma unroll
    for (int r = 0; r < 4; ++r) {
        aA[r] = make_float4(0.f, 0.f, 0.f, 0.f);
        aB[r] = make_float4(0.f, 0.f, 0.f, 0.f);
    }
    const int rb = h * 64;
    const int vb0 = h * 16;
    #pragma unroll 4
    for (int dg = 0; dg < 16; ++dg) {
        const int row = rb + dg * 4;
        const float4 t0 = T4[(row + 0) * 32 + cg];
        const float4 t1 = T4[(row + 1) * 32 + cg];
        const float4 t2 = T4[(row + 2) * 32 + cg];
        const float4 t3 = T4[(row + 3) * 32 + cg];
        const int vi = vb0 + dg;
        #pragma unroll
        for (int r = 0; r < 4; ++r) {
            const float4 va = vA[r * 32 + vi];   // uniform-addr broadcast
            FMA4(aA[r], t0, va.x); FMA4(aA[r], t1, va.y);
            FMA4(aA[r], t2, va.z); FMA4(aA[r], t3, va.w);
            const float4 vbv = vB[r * 32 + vi];
            FMA4(aB[r], t0, vbv.x); FMA4(aB[r], t1, vbv.y);
            FMA4(aB[r], t2, vbv.z); FMA4(aB[r], t3, vbv.w);
        }
    }
    // combine the two d-halves
    #pragma unroll
    for (int r = 0; r < 4; ++r) {
        aA[r].x += __shfl_xor(aA[r].x, 32); aA[r].y += __shfl_xor(aA[r].y, 32);
        aA[r].z += __shfl_xor(aA[r].z, 32); aA[r].w += __shfl_xor(aA[r].w, 32);
        aB[r].x += __shfl_xor(aB[r].x, 32); aB[r].y += __shfl_xor(aB[r].y, 32);
        aB[r].z += __shfl_xor(aB[r].z, 32); aB[r].w += __shfl_xor(aB[r].w, 32);
    }
    wl += sscore(aA, A.rp, A.rn);
    if (hasB) wl += sscore(aB, Bq.rp, Bq.rn);
}

__global__ __launch_bounds__(256, 2) void fused_kernel(
    const float* __restrict__ ent,
    const float* __restrict__ rel,
    const float* __restrict__ tmat,
    const int* __restrict__ pos_h,
    const int* __restrict__ pos_t,
    const int* __restrict__ pos_r,
    const int* __restrict__ neg_h,
    const int* __restrict__ neg_t,
    const int* __restrict__ neg_r,
    const int* __restrict__ ws,
    float* __restrict__ out,
    float inv_B)
{
    const int nit = ws[WS_NITEMS];
    if (blockIdx.x >= nit) return;
    const int4 item = ((const int4*)(ws + WS_ITEMS))[blockIdx.x];
    const int type  = item.x;
    const int start = item.y;
    const int cnt   = item.z;

    const int tid = threadIdx.x;
    const int l   = tid & 63;
    const int w   = tid >> 6;          // wave 0..3
    const int cg  = l & 31;            // column group (cols 4cg..4cg+3)
    const int h   = l >> 5;            // d-half

    __shared__ float T_lds[D * D];     // 64 KB row-major [d][c]
    __shared__ float vbuf[NW][2][4][D];// 16 KB: per-wave {sampleA,B} x role x d

    // stage T: 16 float4/thread, coalesced
    {
        const float4* Tg = (const float4*)(tmat + (size_t)type * (D * D));
        float4* Ts = (float4*)T_lds;
        #pragma unroll
        for (int k = 0; k < 16; ++k)
            Ts[tid + k * 256] = Tg[tid + k * 256];
    }
    __syncthreads();                   // only barrier before the end

    const int* ordr = ws + WS_ORDER;
    float* vbw = &vbuf[w][0][0][0];

    float wl = 0.f;
    int ja = w;
    if (ja < cnt) {
        SampleRegs A0, A1, B0, B1;
        int jb = (ja + NW < cnt) ? ja + NW : ja;
        bool curHasB = (jb != ja);
        fetch_sample(A0, ordr[start + ja], ent, rel, pos_h, pos_t, pos_r,
                     neg_h, neg_t, neg_r, l, cg);
        fetch_sample(A1, ordr[start + jb], ent, rel, pos_h, pos_t, pos_r,
                     neg_h, neg_t, neg_r, l, cg);
        for (;;) {
            commit_sample(vbw,          A0, l);
            commit_sample(vbw + 4 * D,  A1, l);
            const int jn = ja + 2 * NW;
            const bool more = jn < cnt;
            bool nextHasB = false;
            if (more) {
                const int jnb = (jn + NW < cnt) ? jn + NW : jn;
                nextHasB = (jnb != jn);
                fetch_sample(B0, ordr[start + jn], ent, rel, pos_h, pos_t, pos_r,
                             neg_h, neg_t, neg_r, l, cg);
                fetch_sample(B1, ordr[start + jnb], ent, rel, pos_h, pos_t, pos_r,
                             neg_h, neg_t, neg_r, l, cg);
            }
            pair_score(T_lds, vbw, A0, A1, h, cg, curHasB, wl);
            if (!more) break;
            ja = jn; A0 = B0; A1 = B1; curHasB = nextHasB;
        }
    }

    // block reduction via per-wave private LDS slot, one atomic per block
    if (l == 0) vbuf[w][0][0][0] = wl;
    __syncthreads();
    if (tid == 0) {
        float s = 0.f;
        #pragma unroll
        for (int k = 0; k < NW; ++k) s += vbuf[k][0][0][0];
        atomicAdd(out, s * inv_B);
    }
}

// ---------------- fallback (round-1 per-sample kernel) ----------------

__global__ __launch_bounds__(128) void transr_fallback(
    const float* __restrict__ ent, const float* __restrict__ rel,
    const float* __restrict__ tmat,
    const int* __restrict__ pos_h, const int* __restrict__ pos_t,
    const int* __restrict__ pos_r, const int* __restrict__ pos_type_r,
    const int* __restrict__ neg_h, const int* __restrict__ neg_t,
    const int* __restrict__ neg_r, float* __restrict__ out, int B)
{
    const int b = blockIdx.x;
    const int r = threadIdx.x;
    const int lane = r & 63;
    const int wid = r >> 6;
    __shared__ float4 vcomb[D];
    __shared__ float sred[16];
    vcomb[r] = make_float4(ent[(size_t)pos_h[b]*D + r], ent[(size_t)pos_t[b]*D + r],
                           ent[(size_t)neg_h[b]*D + r], ent[(size_t)neg_t[b]*D + r]);
    const float prr = rel[(size_t)pos_r[b] * D + r];
    const float nrr = rel[(size_t)neg_r[b] * D + r];
    __syncthreads();
    const float* __restrict__ T = tmat + (size_t)pos_type_r[b] * (D * D);
    float aph = 0.f, apt = 0.f, anh = 0.f, ant = 0.f;
    #pragma unroll 8
    for (int d = 0; d < D; ++d) {
        const float t = T[d * D + r];
        const float4 v = vcomb[d];
        aph = fmaf(v.x, t, aph); apt = fmaf(v.y, t, apt);
        anh = fmaf(v.z, t, anh); ant = fmaf(v.w, t, ant);
    }
    float s0 = aph*aph, s1 = apt*apt, s2 = anh*anh, s3 = ant*ant;
    float s4 = prr*prr, s5 = nrr*nrr;
    #pragma unroll
    for (int off = 32; off; off >>= 1) {
        s0 += __shfl_xor(s0, off); s1 += __shfl_xor(s1, off);
        s2 += __shfl_xor(s2, off); s3 += __shfl_xor(s3, off);
        s4 += __shfl_xor(s4, off); s5 += __shfl_xor(s5, off);
    }
    if (lane == 0) {
        sred[wid*8+0]=s0; sred[wid*8+1]=s1; sred[wid*8+2]=s2;
        sred[wid*8+3]=s3; sred[wid*8+4]=s4; sred[wid*8+5]=s5;
    }
    __syncthreads();
    const float iph = rsqrtf(sred[0]+sred[8] +1e-12f);
    const float ipt = rsqrtf(sred[1]+sred[9] +1e-12f);
    const float inh = rsqrtf(sred[2]+sred[10]+1e-12f);
    const float itn = rsqrtf(sred[3]+sred[11]+1e-12f);
    const float ipr = rsqrtf(sred[4]+sred[12]+1e-12f);
    const float inr = rsqrtf(sred[5]+sred[13]+1e-12f);
    float pterm = fabsf(aph*iph + prr*ipr - apt*ipt);
    float nterm = fabsf(anh*inh + nrr*inr - ant*itn);
    #pragma unroll
    for (int off = 32; off; off >>= 1) {
        pterm += __shfl_xor(pterm, off);
        nterm += __shfl_xor(nterm, off);
    }
    __syncthreads();
    if (lane == 0) { sred[wid*2+0] = pterm; sred[wid*2+1] = nterm; }
    __syncthreads();
    if (r == 0)
        atomicAdd(out, fmaxf(sred[0]+sred[2] - sred[1]-sred[3] + MARGIN, 0.f) / (float)B);
}

// ---------------- launch ----------------

extern "C" void kernel_launch(void* const* d_in, const int* in_sizes, int n_in,
                              void* d_out, int out_size, void* d_ws, size_t ws_size,
                              hipStream_t stream) {
    const float* ent  = (const float*)d_in[0];
    const float* rel  = (const float*)d_in[1];
    const float* tmat = (const float*)d_in[2];
    const int* pos_h      = (const int*)d_in[3];
    const int* pos_t      = (const int*)d_in[4];
    const int* pos_r      = (const int*)d_in[5];
    const int* pos_type_r = (const int*)d_in[6];
    const int* neg_h      = (const int*)d_in[7];
    const int* neg_t      = (const int*)d_in[8];
    const int* neg_r      = (const int*)d_in[9];
    float* out = (float*)d_out;
    const int B = in_sizes[3];
    const int ntype = in_sizes[2] / (D * D);

    if (ws_size < WS_NEEDED || ntype > MAX_TYPES || B > MAX_B) {
        hipMemsetAsync(out, 0, sizeof(float), stream);
        transr_fallback<<<B, 128, 0, stream>>>(
            ent, rel, tmat, pos_h, pos_t, pos_r, pos_type_r,
            neg_h, neg_t, neg_r, out, B);
        return;
    }

    int* ws = (int*)d_ws;
    group_kernel<<<1, 1024, 0, stream>>>(pos_type_r, ws, out, B, ntype);
    // worst-case nit <= ntype + B/CHUNK = 1024 + 128
    fused_kernel<<<1280, 256, 0, stream>>>(
        ent, rel, tmat, pos_h, pos_t, pos_r, neg_h, neg_t, neg_r,
        ws, out, 1.0f / (float)B);
}

// Round 9
// 48.049 us; speedup vs baseline: 1.1977x; 1.1977x over previous
//
#include <hip/hip_runtime.h>

#define D 128
#define CHUNK 64
#define MAX_TYPES 1024
#define MAX_B 8192
#define MARGIN 1.0f

// ws layout (int units)
#define WS_NITEMS 0
#define WS_ORDER  64                     // B ints (slot -> sample idx)
#define WS_ITEMS  8448                   // int4 x <=2048
#define WS_NEEDED ((size_t)(WS_ITEMS + 4 * 2048) * 4)

// ---------------- fused grouping kernel (1 block, 1024 thr) ----------------

__global__ __launch_bounds__(1024) void group_kernel(
    const int* __restrict__ type_r, int* __restrict__ ws,
    float* __restrict__ out, int B, int ntype)
{
    __shared__ int hist[MAX_TYPES];
    __shared__ int typec[MAX_B];
    __shared__ int wsum[16], wsum2[16];
    const int tid = threadIdx.x;
    const int lane = tid & 63;
    const int wv = tid >> 6;

    if (tid == 0) out[0] = 0.0f;
    hist[tid] = 0;
    __syncthreads();

    const int B4 = B >> 2;
    const int4* t4p = (const int4*)type_r;
    for (int i = tid; i < B4; i += 1024) {
        const int4 t = t4p[i];
        typec[i * 4 + 0] = t.x; atomicAdd(&hist[t.x], 1);
        typec[i * 4 + 1] = t.y; atomicAdd(&hist[t.y], 1);
        typec[i * 4 + 2] = t.z; atomicAdd(&hist[t.z], 1);
        typec[i * 4 + 3] = t.w; atomicAdd(&hist[t.w], 1);
    }
    for (int i = (B4 << 2) + tid; i < B; i += 1024) {
        const int t = type_r[i];
        typec[i] = t;
        atomicAdd(&hist[t], 1);
    }
    __syncthreads();

    const int c  = (tid < ntype) ? hist[tid] : 0;
    const int ic = (c + CHUNK - 1) / CHUNK;
    int vc = c, vic = ic;
    #pragma unroll
    for (int off = 1; off < 64; off <<= 1) {
        const int tc  = __shfl_up(vc,  off);
        const int tic = __shfl_up(vic, off);
        if (lane >= off) { vc += tc; vic += tic; }
    }
    if (lane == 63) { wsum[wv] = vc; wsum2[wv] = vic; }
    __syncthreads();
    if (wv == 0 && lane < 16) {
        int a = wsum[lane], b = wsum2[lane];
        #pragma unroll
        for (int off = 1; off < 16; off <<= 1) {
            const int ta = __shfl_up(a, off);
            const int tb = __shfl_up(b, off);
            if (lane >= off) { a += ta; b += tb; }
        }
        wsum[lane] = a; wsum2[lane] = b;
    }
    __syncthreads();
    const int base_c  = (wv ? wsum[wv - 1]  : 0) + vc - c;
    const int base_ic = (wv ? wsum2[wv - 1] : 0) + vic - ic;
    hist[tid] = base_c;                   // scatter cursor
    if (tid < ntype && ic > 0) {
        int4* items = (int4*)(ws + WS_ITEMS);
        for (int k = 0; k < ic; ++k)
            items[base_ic + k] = make_int4(tid, base_c + k * CHUNK,
                                           min(CHUNK, c - k * CHUNK), 0);
    }
    if (tid == 0) ws[WS_NITEMS] = wsum2[15];
    __syncthreads();
    for (int i = tid; i < B; i += 1024) {
        const int p = atomicAdd(&hist[typec[i]], 1);
        ws[WS_ORDER + p] = i;
    }
}

// ---------------- fused main kernel ----------------
// 512 thr = 8 waves, each wave autonomous, 1 sample per pass.
// lane: cg = l&31 (cols 4cg..+3), h = l>>5 (row half). b128 T + b128 v reads.

#define BFLY5(x) { x += __shfl_xor(x, 1); x += __shfl_xor(x, 2); x += __shfl_xor(x, 4); \
                   x += __shfl_xor(x, 8); x += __shfl_xor(x, 16); }

#define FMA4(A, T, S) { (A).x = fmaf((T).x, (S), (A).x); (A).y = fmaf((T).y, (S), (A).y); \
                        (A).z = fmaf((T).z, (S), (A).z); (A).w = fmaf((T).w, (S), (A).w); }

struct SampleRegs {
    float2 e0, e1, e2, e3;   // ent rows {ph,pt,nh,nt}, elems {2l, 2l+1}
    float4 rp, rn;           // rel rows (pos, neg), cols 4cg..+3
};

__device__ __forceinline__ void fetch_sample(
    SampleRegs& S, int o,
    const float* __restrict__ ent, const float* __restrict__ rel,
    const int* __restrict__ pos_h, const int* __restrict__ pos_t,
    const int* __restrict__ pos_r, const int* __restrict__ neg_h,
    const int* __restrict__ neg_t, const int* __restrict__ neg_r,
    int l, int cg)
{
    const size_t b0 = (size_t)pos_h[o] * D;
    const size_t b1 = (size_t)pos_t[o] * D;
    const size_t b2 = (size_t)neg_h[o] * D;
    const size_t b3 = (size_t)neg_t[o] * D;
    const size_t r0 = (size_t)pos_r[o] * D;
    const size_t r1 = (size_t)neg_r[o] * D;
    S.e0 = *(const float2*)&ent[b0 + 2 * l];
    S.e1 = *(const float2*)&ent[b1 + 2 * l];
    S.e2 = *(const float2*)&ent[b2 + 2 * l];
    S.e3 = *(const float2*)&ent[b3 + 2 * l];
    S.rp = *(const float4*)&rel[r0 + 4 * cg];
    S.rn = *(const float4*)&rel[r1 + 4 * cg];
}

__device__ __forceinline__ void commit_sample(float* vbw, const SampleRegs& S, int l) {
    *(float2*)&vbw[0 * D + 2 * l] = S.e0;
    *(float2*)&vbw[1 * D + 2 * l] = S.e1;
    *(float2*)&vbw[2 * D + 2 * l] = S.e2;
    *(float2*)&vbw[3 * D + 2 * l] = S.e3;
}

// matvec for ONE sample + full score, within one wave.
__device__ __forceinline__ float sample_score(
    const float* __restrict__ T_lds, const float* __restrict__ vbw,
    int h, int cg, float4 rp, float4 rn)
{
    const float4* __restrict__ T4 = (const float4*)T_lds;   // [row][32]
    const float4* __restrict__ vv = (const float4*)vbw;     // [4 roles][32]
    float4 a0 = make_float4(0.f, 0.f, 0.f, 0.f), a1 = a0, a2 = a0, a3 = a0;
    const int rb  = h * 64;       // row base
    const int vb0 = h * 16;       // v float4 base
    #pragma unroll 4
    for (int dg = 0; dg < 16; ++dg) {
        const int row = rb + dg * 4;
        const float4 t0 = T4[(row + 0) * 32 + cg];
        const float4 t1 = T4[(row + 1) * 32 + cg];
        const float4 t2 = T4[(row + 2) * 32 + cg];
        const float4 t3 = T4[(row + 3) * 32 + cg];
        const int vi = vb0 + dg;
        const float4 v0 = vv[0 * 32 + vi];   // 2-addr multicast (free)
        FMA4(a0, t0, v0.x); FMA4(a0, t1, v0.y); FMA4(a0, t2, v0.z); FMA4(a0, t3, v0.w);
        const float4 v1 = vv[1 * 32 + vi];
        FMA4(a1, t0, v1.x); FMA4(a1, t1, v1.y); FMA4(a1, t2, v1.z); FMA4(a1, t3, v1.w);
        const float4 v2 = vv[2 * 32 + vi];
        FMA4(a2, t0, v2.x); FMA4(a2, t1, v2.y); FMA4(a2, t2, v2.z); FMA4(a2, t3, v2.w);
        const float4 v3 = vv[3 * 32 + vi];
        FMA4(a3, t0, v3.x); FMA4(a3, t1, v3.y); FMA4(a3, t2, v3.z); FMA4(a3, t3, v3.w);
    }
    // combine the two row-halves (lanes l <-> l+32)
    a0.x += __shfl_xor(a0.x, 32); a0.y += __shfl_xor(a0.y, 32);
    a0.z += __shfl_xor(a0.z, 32); a0.w += __shfl_xor(a0.w, 32);
    a1.x += __shfl_xor(a1.x, 32); a1.y += __shfl_xor(a1.y, 32);
    a1.z += __shfl_xor(a1.z, 32); a1.w += __shfl_xor(a1.w, 32);
    a2.x += __shfl_xor(a2.x, 32); a2.y += __shfl_xor(a2.y, 32);
    a2.z += __shfl_xor(a2.z, 32); a2.w += __shfl_xor(a2.w, 32);
    a3.x += __shfl_xor(a3.x, 32); a3.y += __shfl_xor(a3.y, 32);
    a3.z += __shfl_xor(a3.z, 32); a3.w += __shfl_xor(a3.w, 32);

    float sph = a0.x*a0.x + a0.y*a0.y + a0.z*a0.z + a0.w*a0.w;
    float spt = a1.x*a1.x + a1.y*a1.y + a1.z*a1.z + a1.w*a1.w;
    float snh = a2.x*a2.x + a2.y*a2.y + a2.z*a2.z + a2.w*a2.w;
    float snt = a3.x*a3.x + a3.y*a3.y + a3.z*a3.z + a3.w*a3.w;
    float spr = rp.x*rp.x + rp.y*rp.y + rp.z*rp.z + rp.w*rp.w;
    float snr = rn.x*rn.x + rn.y*rn.y + rn.z*rn.z + rn.w*rn.w;
    BFLY5(sph); BFLY5(spt); BFLY5(snh); BFLY5(snt); BFLY5(spr); BFLY5(snr);
    const float iph = rsqrtf(sph + 1e-12f);
    const float ipt = rsqrtf(spt + 1e-12f);
    const float inh = rsqrtf(snh + 1e-12f);
    const float itn = rsqrtf(snt + 1e-12f);
    const float ipr = rsqrtf(spr + 1e-12f);
    const float inr = rsqrtf(snr + 1e-12f);
    float z = fabsf(a0.x*iph + rp.x*ipr - a1.x*ipt)
            + fabsf(a0.y*iph + rp.y*ipr - a1.y*ipt)
            + fabsf(a0.z*iph + rp.z*ipr - a1.z*ipt)
            + fabsf(a0.w*iph + rp.w*ipr - a1.w*ipt)
            - fabsf(a2.x*inh + rn.x*inr - a3.x*itn)
            - fabsf(a2.y*inh + rn.y*inr - a3.y*itn)
            - fabsf(a2.z*inh + rn.z*inr - a3.z*itn)
            - fabsf(a2.w*inh + rn.w*inr - a3.w*itn);
    BFLY5(z);
    return fmaxf(z + MARGIN, 0.f);
}

__global__ __launch_bounds__(512, 4) void fused_kernel(
    const float* __restrict__ ent,
    const float* __restrict__ rel,
    const float* __restrict__ tmat,
    const int* __restrict__ pos_h,
    const int* __restrict__ pos_t,
    const int* __restrict__ pos_r,
    const int* __restrict__ neg_h,
    const int* __restrict__ neg_t,
    const int* __restrict__ neg_r,
    const int* __restrict__ ws,
    float* __restrict__ out,
    float inv_B)
{
    const int nit = ws[WS_NITEMS];
    if (blockIdx.x >= nit) return;
    const int4 item = ((const int4*)(ws + WS_ITEMS))[blockIdx.x];
    const int type  = item.x;
    const int start = item.y;
    const int cnt   = item.z;

    const int tid = threadIdx.x;
    const int l   = tid & 63;
    const int w   = tid >> 6;          // wave 0..7
    const int cg  = l & 31;
    const int h   = l >> 5;

    __shared__ float T_lds[D * D];     // 64 KB row-major [d][c]
    __shared__ float vbuf[8][4][D];    // 16 KB per-wave role-major

    const int* ordr = ws + WS_ORDER;

    // issue this wave's FIRST gather before T staging (hides HBM latency)
    SampleRegs A, Bq;
    int j = w;
    const bool active = (j < cnt);
    if (active)
        fetch_sample(A, ordr[start + j], ent, rel, pos_h, pos_t, pos_r,
                     neg_h, neg_t, neg_r, l, cg);

    // stage T: 8 float4/thread, coalesced, layout-preserving
    {
        const float4* Tg = (const float4*)(tmat + (size_t)type * (D * D));
        float4* Ts = (float4*)T_lds;
        #pragma unroll
        for (int k = 0; k < 8; ++k)
            Ts[tid + k * 512] = Tg[tid + k * 512];
    }
    __syncthreads();                   // only barrier before the end

    float* vbw = &vbuf[w][0][0];
    float wl = 0.f;

    if (active) {
        for (;;) {
            commit_sample(vbw, A, l);
            const int jn = j + 8;
            const bool more = jn < cnt;
            if (more)
                fetch_sample(Bq, ordr[start + jn], ent, rel, pos_h, pos_t, pos_r,
                             neg_h, neg_t, neg_r, l, cg);
            wl += sample_score(T_lds, vbw, h, cg, A.rp, A.rn);
            if (!more) break;
            j = jn; A = Bq;
        }
    }

    // block reduction via per-wave private LDS slot, one atomic per block
    if (l == 0) vbuf[w][0][0] = wl;
    __syncthreads();
    if (tid == 0) {
        float s = 0.f;
        #pragma unroll
        for (int k = 0; k < 8; ++k) s += vbuf[k][0][0];
        atomicAdd(out, s * inv_B);
    }
}

// ---------------- fallback (round-1 per-sample kernel) ----------------

__global__ __launch_bounds__(128) void transr_fallback(
    const float* __restrict__ ent, const float* __restrict__ rel,
    const float* __restrict__ tmat,
    const int* __restrict__ pos_h, const int* __restrict__ pos_t,
    const int* __restrict__ pos_r, const int* __restrict__ pos_type_r,
    const int* __restrict__ neg_h, const int* __restrict__ neg_t,
    const int* __restrict__ neg_r, float* __restrict__ out, int B)
{
    const int b = blockIdx.x;
    const int r = threadIdx.x;
    const int lane = r & 63;
    const int wid = r >> 6;
    __shared__ float4 vcomb[D];
    __shared__ float sred[16];
    vcomb[r] = make_float4(ent[(size_t)pos_h[b]*D + r], ent[(size_t)pos_t[b]*D + r],
                           ent[(size_t)neg_h[b]*D + r], ent[(size_t)neg_t[b]*D + r]);
    const float prr = rel[(size_t)pos_r[b] * D + r];
    const float nrr = rel[(size_t)neg_r[b] * D + r];
    __syncthreads();
    const float* __restrict__ T = tmat + (size_t)pos_type_r[b] * (D * D);
    float aph = 0.f, apt = 0.f, anh = 0.f, ant = 0.f;
    #pragma unroll 8
    for (int d = 0; d < D; ++d) {
        const float t = T[d * D + r];
        const float4 v = vcomb[d];
        aph = fmaf(v.x, t, aph); apt = fmaf(v.y, t, apt);
        anh = fmaf(v.z, t, anh); ant = fmaf(v.w, t, ant);
    }
    float s0 = aph*aph, s1 = apt*apt, s2 = anh*anh, s3 = ant*ant;
    float s4 = prr*prr, s5 = nrr*nrr;
    #pragma unroll
    for (int off = 32; off; off >>= 1) {
        s0 += __shfl_xor(s0, off); s1 += __shfl_xor(s1, off);
        s2 += __shfl_xor(s2, off); s3 += __shfl_xor(s3, off);
        s4 += __shfl_xor(s4, off); s5 += __shfl_xor(s5, off);
    }
    if (lane == 0) {
        sred[wid*8+0]=s0; sred[wid*8+1]=s1; sred[wid*8+2]=s2;
        sred[wid*8+3]=s3; sred[wid*8+4]=s4; sred[wid*8+5]=s5;
    }
    __syncthreads();
    const float iph = rsqrtf(sred[0]+sred[8] +1e-12f);
    const float ipt = rsqrtf(sred[1]+sred[9] +1e-12f);
    const float inh = rsqrtf(sred[2]+sred[10]+1e-12f);
    const float itn = rsqrtf(sred[3]+sred[11]+1e-12f);
    const float ipr = rsqrtf(sred[4]+sred[12]+1e-12f);
    const float inr = rsqrtf(sred[5]+sred[13]+1e-12f);
    float pterm = fabsf(aph*iph + prr*ipr - apt*ipt);
    float nterm = fabsf(anh*inh + nrr*inr - ant*itn);
    #pragma unroll
    for (int off = 32; off; off >>= 1) {
        pterm += __shfl_xor(pterm, off);
        nterm += __shfl_xor(nterm, off);
    }
    __syncthreads();
    if (lane == 0) { sred[wid*2+0] = pterm; sred[wid*2+1] = nterm; }
    __syncthreads();
    if (r == 0)
        atomicAdd(out, fmaxf(sred[0]+sred[2] - sred[1]-sred[3] + MARGIN, 0.f) / (float)B);
}

// ---------------- launch ----------------

extern "C" void kernel_launch(void* const* d_in, const int* in_sizes, int n_in,
                              void* d_out, int out_size, void* d_ws, size_t ws_size,
                              hipStream_t stream) {
    const float* ent  = (const float*)d_in[0];
    const float* rel  = (const float*)d_in[1];
    const float* tmat = (const float*)d_in[2];
    const int* pos_h      = (const int*)d_in[3];
    const int* pos_t      = (const int*)d_in[4];
    const int* pos_r      = (const int*)d_in[5];
    const int* pos_type_r = (const int*)d_in[6];
    const int* neg_h      = (const int*)d_in[7];
    const int* neg_t      = (const int*)d_in[8];
    const int* neg_r      = (const int*)d_in[9];
    float* out = (float*)d_out;
    const int B = in_sizes[3];
    const int ntype = in_sizes[2] / (D * D);

    if (ws_size < WS_NEEDED || ntype > MAX_TYPES || B > MAX_B) {
        hipMemsetAsync(out, 0, sizeof(float), stream);
        transr_fallback<<<B, 128, 0, stream>>>(
            ent, rel, tmat, pos_h, pos_t, pos_r, pos_type_r,
            neg_h, neg_t, neg_r, out, B);
        return;
    }

    int* ws = (int*)d_ws;
    group_kernel<<<1, 1024, 0, stream>>>(pos_type_r, ws, out, B, ntype);
    // worst-case nit <= ntype + B/CHUNK = 1024 + 128
    fused_kernel<<<1280, 512, 0, stream>>>(
        ent, rel, tmat, pos_h, pos_t, pos_r, neg_h, neg_t, neg_r,
        ws, out, 1.0f / (float)B);
}

// Round 10
// 46.607 us; speedup vs baseline: 1.2348x; 1.0309x over previous
//
#include <hip/hip_runtime.h>

#define D 128
#define MAX_B 8192
#define MARGIN 1.0f

// ---------------- fused single kernel: block == type ----------------
// 512 thr = 8 waves. Each block scans pos_type_r for its type, builds an
// ordered sample list in LDS scratch, then each wave processes its samples
// autonomously (round-9 matvec: b128 T reads, b128 v-broadcasts, shfl epilogue).

#define BFLY5(x) { x += __shfl_xor(x, 1); x += __shfl_xor(x, 2); x += __shfl_xor(x, 4); \
                   x += __shfl_xor(x, 8); x += __shfl_xor(x, 16); }

#define FMA4(A, T, S) { (A).x = fmaf((T).x, (S), (A).x); (A).y = fmaf((T).y, (S), (A).y); \
                        (A).z = fmaf((T).z, (S), (A).z); (A).w = fmaf((T).w, (S), (A).w); }

struct SampleRegs {
    float2 e0, e1, e2, e3;   // ent rows {ph,pt,nh,nt}, elems {2l, 2l+1}
    float4 rp, rn;           // rel rows (pos, neg), cols 4cg..+3
};

__device__ __forceinline__ void fetch_sample(
    SampleRegs& S, int o,
    const float* __restrict__ ent, const float* __restrict__ rel,
    const int* __restrict__ pos_h, const int* __restrict__ pos_t,
    const int* __restrict__ pos_r, const int* __restrict__ neg_h,
    const int* __restrict__ neg_t, const int* __restrict__ neg_r,
    int l, int cg)
{
    const size_t b0 = (size_t)pos_h[o] * D;
    const size_t b1 = (size_t)pos_t[o] * D;
    const size_t b2 = (size_t)neg_h[o] * D;
    const size_t b3 = (size_t)neg_t[o] * D;
    const size_t r0 = (size_t)pos_r[o] * D;
    const size_t r1 = (size_t)neg_r[o] * D;
    S.e0 = *(const float2*)&ent[b0 + 2 * l];
    S.e1 = *(const float2*)&ent[b1 + 2 * l];
    S.e2 = *(const float2*)&ent[b2 + 2 * l];
    S.e3 = *(const float2*)&ent[b3 + 2 * l];
    S.rp = *(const float4*)&rel[r0 + 4 * cg];
    S.rn = *(const float4*)&rel[r1 + 4 * cg];
}

__device__ __forceinline__ void commit_sample(float* vbw, const SampleRegs& S, int l) {
    *(float2*)&vbw[0 * D + 2 * l] = S.e0;
    *(float2*)&vbw[1 * D + 2 * l] = S.e1;
    *(float2*)&vbw[2 * D + 2 * l] = S.e2;
    *(float2*)&vbw[3 * D + 2 * l] = S.e3;
}

// matvec for ONE sample + full score, within one wave (round-9 proven body).
__device__ __forceinline__ float sample_score(
    const float* __restrict__ T_lds, const float* __restrict__ vbw,
    int h, int cg, float4 rp, float4 rn)
{
    const float4* __restrict__ T4 = (const float4*)T_lds;   // [row][32]
    const float4* __restrict__ vv = (const float4*)vbw;     // [4 roles][32]
    float4 a0 = make_float4(0.f, 0.f, 0.f, 0.f), a1 = a0, a2 = a0, a3 = a0;
    const int rb  = h * 64;
    const int vb0 = h * 16;
    #pragma unroll 4
    for (int dg = 0; dg < 16; ++dg) {
        const int row = rb + dg * 4;
        const float4 t0 = T4[(row + 0) * 32 + cg];
        const float4 t1 = T4[(row + 1) * 32 + cg];
        const float4 t2 = T4[(row + 2) * 32 + cg];
        const float4 t3 = T4[(row + 3) * 32 + cg];
        const int vi = vb0 + dg;
        const float4 v0 = vv[0 * 32 + vi];
        FMA4(a0, t0, v0.x); FMA4(a0, t1, v0.y); FMA4(a0, t2, v0.z); FMA4(a0, t3, v0.w);
        const float4 v1 = vv[1 * 32 + vi];
        FMA4(a1, t0, v1.x); FMA4(a1, t1, v1.y); FMA4(a1, t2, v1.z); FMA4(a1, t3, v1.w);
        const float4 v2 = vv[2 * 32 + vi];
        FMA4(a2, t0, v2.x); FMA4(a2, t1, v2.y); FMA4(a2, t2, v2.z); FMA4(a2, t3, v2.w);
        const float4 v3 = vv[3 * 32 + vi];
        FMA4(a3, t0, v3.x); FMA4(a3, t1, v3.y); FMA4(a3, t2, v3.z); FMA4(a3, t3, v3.w);
    }
    a0.x += __shfl_xor(a0.x, 32); a0.y += __shfl_xor(a0.y, 32);
    a0.z += __shfl_xor(a0.z, 32); a0.w += __shfl_xor(a0.w, 32);
    a1.x += __shfl_xor(a1.x, 32); a1.y += __shfl_xor(a1.y, 32);
    a1.z += __shfl_xor(a1.z, 32); a1.w += __shfl_xor(a1.w, 32);
    a2.x += __shfl_xor(a2.x, 32); a2.y += __shfl_xor(a2.y, 32);
    a2.z += __shfl_xor(a2.z, 32); a2.w += __shfl_xor(a2.w, 32);
    a3.x += __shfl_xor(a3.x, 32); a3.y += __shfl_xor(a3.y, 32);
    a3.z += __shfl_xor(a3.z, 32); a3.w += __shfl_xor(a3.w, 32);

    float sph = a0.x*a0.x + a0.y*a0.y + a0.z*a0.z + a0.w*a0.w;
    float spt = a1.x*a1.x + a1.y*a1.y + a1.z*a1.z + a1.w*a1.w;
    float snh = a2.x*a2.x + a2.y*a2.y + a2.z*a2.z + a2.w*a2.w;
    float snt = a3.x*a3.x + a3.y*a3.y + a3.z*a3.z + a3.w*a3.w;
    float spr = rp.x*rp.x + rp.y*rp.y + rp.z*rp.z + rp.w*rp.w;
    float snr = rn.x*rn.x + rn.y*rn.y + rn.z*rn.z + rn.w*rn.w;
    BFLY5(sph); BFLY5(spt); BFLY5(snh); BFLY5(snt); BFLY5(spr); BFLY5(snr);
    const float iph = rsqrtf(sph + 1e-12f);
    const float ipt = rsqrtf(spt + 1e-12f);
    const float inh = rsqrtf(snh + 1e-12f);
    const float itn = rsqrtf(snt + 1e-12f);
    const float ipr = rsqrtf(spr + 1e-12f);
    const float inr = rsqrtf(snr + 1e-12f);
    float z = fabsf(a0.x*iph + rp.x*ipr - a1.x*ipt)
            + fabsf(a0.y*iph + rp.y*ipr - a1.y*ipt)
            + fabsf(a0.z*iph + rp.z*ipr - a1.z*ipt)
            + fabsf(a0.w*iph + rp.w*ipr - a1.w*ipt)
            - fabsf(a2.x*inh + rn.x*inr - a3.x*itn)
            - fabsf(a2.y*inh + rn.y*inr - a3.y*itn)
            - fabsf(a2.z*inh + rn.z*inr - a3.z*itn)
            - fabsf(a2.w*inh + rn.w*inr - a3.w*itn);
    BFLY5(z);
    return fmaxf(z + MARGIN, 0.f);
}

__global__ __launch_bounds__(512, 4) void fused_kernel(
    const float* __restrict__ ent,
    const float* __restrict__ rel,
    const float* __restrict__ tmat,
    const int* __restrict__ pos_h,
    const int* __restrict__ pos_t,
    const int* __restrict__ pos_r,
    const int* __restrict__ type_r,
    const int* __restrict__ neg_h,
    const int* __restrict__ neg_t,
    const int* __restrict__ neg_r,
    float* __restrict__ out,
    int B, float inv_B)
{
    const int t   = blockIdx.x;        // this block's type
    const int tid = threadIdx.x;
    const int l   = tid & 63;
    const int w   = tid >> 6;          // wave 0..7
    const int cg  = l & 31;
    const int h   = l >> 5;

    __shared__ float T_lds[D * D];     // 64 KB row-major [d][c]
    __shared__ float vbuf[8][4][D];    // 16 KB per-wave role-major (+scratch alias)
    int* lsc = (int*)&vbuf[0][0][0];   // scratch view (list[0..63], wave sums 64..71)

    // ---- issue T staging loads (in flight during the scan) ----
    float4 ts[8];
    {
        const float4* Tg = (const float4*)(tmat + (size_t)t * (D * D));
        #pragma unroll
        for (int k = 0; k < 8; ++k)
            ts[k] = Tg[tid + k * 512];
    }

    // ---- scan pos_type_r: thread tid covers samples [tid*per, +per) ----
    const int per = (B + 511) >> 9;    // == 16 at B=8192
    int vals[16];
    const int base = tid * per;
    int mc = 0;
    if (per == 16 && base + 15 < B) {
        const int4* vp = (const int4*)(type_r + base);
        #pragma unroll
        for (int k = 0; k < 4; ++k) {
            const int4 v = vp[k];
            vals[4*k+0] = v.x; vals[4*k+1] = v.y;
            vals[4*k+2] = v.z; vals[4*k+3] = v.w;
        }
    } else {
        for (int j = 0; j < 16; ++j) {
            const int s = base + j;
            vals[j] = (j < per && s < B) ? type_r[s] : -1;
        }
    }
    #pragma unroll
    for (int j = 0; j < 16; ++j) mc += (vals[j] == t);

    // ---- write T to LDS (loads have had the scan to cover latency) ----
    {
        float4* Ts = (float4*)T_lds;
        #pragma unroll
        for (int k = 0; k < 8; ++k)
            Ts[tid + k * 512] = ts[k];
    }

    // ---- block-wide exclusive prefix of mc ----
    int inc = mc;
    #pragma unroll
    for (int off = 1; off < 64; off <<= 1) {
        const int tv = __shfl_up(inc, off);
        if (l >= off) inc += tv;
    }
    if (l == 63) lsc[64 + w] = inc;
    __syncthreads();                   // wave totals visible (T writes too)
    int wbase = 0, cnt = 0;
    #pragma unroll
    for (int k = 0; k < 8; ++k) {
        const int s = lsc[64 + k];
        wbase += (k < w) ? s : 0;
        cnt += s;
    }
    const int excl = wbase + inc - mc;
    __syncthreads();                   // totals consumed before list overwrite

    float wl = 0.f;
    for (int r0 = 0;; r0 += 64) {
        // write this round's window [r0, r0+64) of the ordered match list
        {
            int g = excl;
            #pragma unroll
            for (int j = 0; j < 16; ++j) {
                if (vals[j] == t) {
                    const int wr = g - r0;
                    if (wr >= 0 && wr < 64) lsc[wr] = base + j;
                    ++g;
                }
            }
        }
        __syncthreads();               // list visible
        const int wcnt = min(cnt - r0, 64);
        int sidx[8];
        int nk = 0;
        #pragma unroll
        for (int k = 0; k < 8; ++k) {
            const int rank = w + 8 * k;
            if (rank < wcnt) sidx[nk++] = lsc[rank];
        }
        __syncthreads();               // all reads done before vbuf overwrite

        if (nk > 0) {
            float* vbw = &vbuf[w][0][0];
            SampleRegs A, Bq;
            fetch_sample(A, sidx[0], ent, rel, pos_h, pos_t, pos_r,
                         neg_h, neg_t, neg_r, l, cg);
            for (int k = 0;; ++k) {
                commit_sample(vbw, A, l);
                const bool more = (k + 1) < nk;
                if (more)
                    fetch_sample(Bq, sidx[k + 1], ent, rel, pos_h, pos_t, pos_r,
                                 neg_h, neg_t, neg_r, l, cg);
                wl += sample_score(T_lds, vbw, h, cg, A.rp, A.rn);
                if (!more) break;
                A = Bq;
            }
        }
        if (r0 + 64 >= cnt) break;
        __syncthreads();               // processing done before next list write
    }

    // ---- block reduction, one atomic ----
    __syncthreads();
    if (l == 0) ((float*)lsc)[w] = wl;
    __syncthreads();
    if (tid == 0) {
        float s = 0.f;
        #pragma unroll
        for (int k = 0; k < 8; ++k) s += ((float*)lsc)[k];
        if (s != 0.f) atomicAdd(out, s * inv_B);
    }
}

// ---------------- fallback (round-1 per-sample kernel) ----------------

__global__ __launch_bounds__(128) void transr_fallback(
    const float* __restrict__ ent, const float* __restrict__ rel,
    const float* __restrict__ tmat,
    const int* __restrict__ pos_h, const int* __restrict__ pos_t,
    const int* __restrict__ pos_r, const int* __restrict__ pos_type_r,
    const int* __restrict__ neg_h, const int* __restrict__ neg_t,
    const int* __restrict__ neg_r, float* __restrict__ out, int B)
{
    const int b = blockIdx.x;
    const int r = threadIdx.x;
    const int lane = r & 63;
    const int wid = r >> 6;
    __shared__ float4 vcomb[D];
    __shared__ float sred[16];
    vcomb[r] = make_float4(ent[(size_t)pos_h[b]*D + r], ent[(size_t)pos_t[b]*D + r],
                           ent[(size_t)neg_h[b]*D + r], ent[(size_t)neg_t[b]*D + r]);
    const float prr = rel[(size_t)pos_r[b] * D + r];
    const float nrr = rel[(size_t)neg_r[b] * D + r];
    __syncthreads();
    const float* __restrict__ T = tmat + (size_t)pos_type_r[b] * (D * D);
    float aph = 0.f, apt = 0.f, anh = 0.f, ant = 0.f;
    #pragma unroll 8
    for (int d = 0; d < D; ++d) {
        const float t = T[d * D + r];
        const float4 v = vcomb[d];
        aph = fmaf(v.x, t, aph); apt = fmaf(v.y, t, apt);
        anh = fmaf(v.z, t, anh); ant = fmaf(v.w, t, ant);
    }
    float s0 = aph*aph, s1 = apt*apt, s2 = anh*anh, s3 = ant*ant;
    float s4 = prr*prr, s5 = nrr*nrr;
    #pragma unroll
    for (int off = 32; off; off >>= 1) {
        s0 += __shfl_xor(s0, off); s1 += __shfl_xor(s1, off);
        s2 += __shfl_xor(s2, off); s3 += __shfl_xor(s3, off);
        s4 += __shfl_xor(s4, off); s5 += __shfl_xor(s5, off);
    }
    if (lane == 0) {
        sred[wid*8+0]=s0; sred[wid*8+1]=s1; sred[wid*8+2]=s2;
        sred[wid*8+3]=s3; sred[wid*8+4]=s4; sred[wid*8+5]=s5;
    }
    __syncthreads();
    const float iph = rsqrtf(sred[0]+sred[8] +1e-12f);
    const float ipt = rsqrtf(sred[1]+sred[9] +1e-12f);
    const float inh = rsqrtf(sred[2]+sred[10]+1e-12f);
    const float itn = rsqrtf(sred[3]+sred[11]+1e-12f);
    const float ipr = rsqrtf(sred[4]+sred[12]+1e-12f);
    const float inr = rsqrtf(sred[5]+sred[13]+1e-12f);
    float pterm = fabsf(aph*iph + prr*ipr - apt*ipt);
    float nterm = fabsf(anh*inh + nrr*inr - ant*itn);
    #pragma unroll
    for (int off = 32; off; off >>= 1) {
        pterm += __shfl_xor(pterm, off);
        nterm += __shfl_xor(nterm, off);
    }
    __syncthreads();
    if (lane == 0) { sred[wid*2+0] = pterm; sred[wid*2+1] = nterm; }
    __syncthreads();
    if (r == 0)
        atomicAdd(out, fmaxf(sred[0]+sred[2] - sred[1]-sred[3] + MARGIN, 0.f) / (float)B);
}

// ---------------- launch ----------------

extern "C" void kernel_launch(void* const* d_in, const int* in_sizes, int n_in,
                              void* d_out, int out_size, void* d_ws, size_t ws_size,
                              hipStream_t stream) {
    const float* ent  = (const float*)d_in[0];
    const float* rel  = (const float*)d_in[1];
    const float* tmat = (const float*)d_in[2];
    const int* pos_h      = (const int*)d_in[3];
    const int* pos_t      = (const int*)d_in[4];
    const int* pos_r      = (const int*)d_in[5];
    const int* pos_type_r = (const int*)d_in[6];
    const int* neg_h      = (const int*)d_in[7];
    const int* neg_t      = (const int*)d_in[8];
    const int* neg_r      = (const int*)d_in[9];
    float* out = (float*)d_out;
    const int B = in_sizes[3];
    const int ntype = in_sizes[2] / (D * D);

    hipMemsetAsync(out, 0, sizeof(float), stream);

    if (B > MAX_B) {
        transr_fallback<<<B, 128, 0, stream>>>(
            ent, rel, tmat, pos_h, pos_t, pos_r, pos_type_r,
            neg_h, neg_t, neg_r, out, B);
        return;
    }

    fused_kernel<<<ntype, 512, 0, stream>>>(
        ent, rel, tmat, pos_h, pos_t, pos_r, pos_type_r,
        neg_h, neg_t, neg_r, out, B, 1.0f / (float)B);
}